// Round 6
// baseline (374.727 us; speedup 1.0000x reference)
//
#include <hip/hip_runtime.h>
#include <hip/hip_bf16.h>
#include <cstdint>
#include <cstddef>

#define Bdim 2
#define Tdim 2048
#define Ddim 2048
#define NHq  16
#define NKV  4
#define HD   128
#define SCALE 0.08838834764831845f
// SCALE * log2(e): folded into q inside flash's Q-rope so softmax runs in exp2 domain
#define QPRESCALE (0.08838834764831845f * 1.4426950408889634f)
#define NEG_INF (-3.0e38f)
// defer-max threshold (log2 domain): e-domain 8 -> 8*log2e ~ 11.5
#define DEFER_THR 11.5f

typedef unsigned short u16;
typedef unsigned int   u32;
typedef __bf16 bf16x8 __attribute__((ext_vector_type(8)));
typedef float  f32x4  __attribute__((ext_vector_type(4)));

__device__ __forceinline__ u16 f2bf(float f) {
    unsigned int u = __float_as_uint(f);
    u += 0x7FFFu + ((u >> 16) & 1u);   // RNE
    return (u16)(u >> 16);
}
__device__ __forceinline__ u16 f2bfn(float f) {
    __bf16 h = (__bf16)f;
    return __builtin_bit_cast(u16, h);
}
__device__ __forceinline__ float bf2f(u16 s) {
    return __uint_as_float(((unsigned int)s) << 16);
}

#if __has_builtin(__builtin_amdgcn_permlane16_swap) && __has_builtin(__builtin_amdgcn_permlane32_swap)
#define HAVE_PERMLANE_SWAP 1
#endif

__device__ __forceinline__ float quad_reduce_max(float v) {
#ifdef HAVE_PERMLANE_SWAP
    auto r = __builtin_amdgcn_permlane16_swap(__float_as_uint(v), __float_as_uint(v), false, false);
    float m = fmaxf(__uint_as_float(r[0]), __uint_as_float(r[1]));
    auto r2 = __builtin_amdgcn_permlane32_swap(__float_as_uint(m), __float_as_uint(m), false, false);
    return fmaxf(__uint_as_float(r2[0]), __uint_as_float(r2[1]));
#else
    v = fmaxf(v, __shfl_xor(v, 16));
    return fmaxf(v, __shfl_xor(v, 32));
#endif
}
__device__ __forceinline__ float quad_reduce_sum(float v) {
#ifdef HAVE_PERMLANE_SWAP
    auto r = __builtin_amdgcn_permlane16_swap(__float_as_uint(v), __float_as_uint(v), false, false);
    float s = __uint_as_float(r[0]) + __uint_as_float(r[1]);
    auto r2 = __builtin_amdgcn_permlane32_swap(__float_as_uint(s), __float_as_uint(s), false, false);
    return __uint_as_float(r2[0]) + __uint_as_float(r2[1]);
#else
    v += __shfl_xor(v, 16);
    return v + __shfl_xor(v, 32);
#endif
}

__device__ __forceinline__ float tree_max16(const float (&s)[16]) {
    float a0 = fmaxf(s[0], s[1]),  a1 = fmaxf(s[2], s[3]);
    float a2 = fmaxf(s[4], s[5]),  a3 = fmaxf(s[6], s[7]);
    float a4 = fmaxf(s[8], s[9]),  a5 = fmaxf(s[10], s[11]);
    float a6 = fmaxf(s[12], s[13]), a7 = fmaxf(s[14], s[15]);
    float b0 = fmaxf(a0, a1), b1 = fmaxf(a2, a3);
    float b2 = fmaxf(a4, a5), b3 = fmaxf(a6, a7);
    return fmaxf(fmaxf(b0, b1), fmaxf(b2, b3));
}
__device__ __forceinline__ float tree_sum16(const float (&s)[16]) {
    float a0 = s[0] + s[1],  a1 = s[2] + s[3];
    float a2 = s[4] + s[5],  a3 = s[6] + s[7];
    float a4 = s[8] + s[9],  a5 = s[10] + s[11];
    float a6 = s[12] + s[13], a7 = s[14] + s[15];
    float b0 = a0 + a1, b1 = a2 + a3, b2 = a4 + a5, b3 = a6 + a7;
    return (b0 + b1) + (b2 + b3);
}

// async global->LDS, 16B per lane. LDS dest is wave-uniform base + lane*16.
typedef __attribute__((address_space(1))) const u32 gbl_u32;
typedef __attribute__((address_space(3))) u32 lds_u32;
__device__ __forceinline__ void gload16(const void* g, void* l) {
    __builtin_amdgcn_global_load_lds((gbl_u32*)(uintptr_t)g, (lds_u32*)(uintptr_t)l, 16, 0, 0);
}

#define VM8 asm volatile("s_waitcnt vmcnt(8)" ::: "memory")
#define VM4 asm volatile("s_waitcnt vmcnt(4)" ::: "memory")
#define VM0 asm volatile("s_waitcnt vmcnt(0)" ::: "memory")
#define VMNONE ((void)0)
#define BARRIER do { asm volatile("" ::: "memory"); __builtin_amdgcn_s_barrier(); asm volatile("" ::: "memory"); } while (0)

// ---------------------------------------------------------------------------
// prep_all: ONE kernel for all input conversion (replaces cvt_x + 4x cvt_w_t;
// saves 4 dispatch boundaries ~10us each).
// blocks [0,8192):       fp32->bf16 copy of Xq,Xkv (8 elems/thread)
// blocks [8192,10752):   W[R][C] -> bf16 W^T[C][R] 64x64 tiles
//   Wk additionally gets a per-head ROW PERMUTATION tau^-1 (j4<-c6, j5<-c4,
//   j6<-c5) so that in the qkv epilogue each thread's acc holds BOTH RoPE
//   rotation halves (pairs land in nf=2p / nf=2p+1) -> thread-local K-rope.
// ---------------------------------------------------------------------------
__global__ __launch_bounds__(256) void prep_all(const float* __restrict__ Xq,
                                                const float* __restrict__ Xkv,
                                                const float* __restrict__ Wq,
                                                const float* __restrict__ Wk,
                                                const float* __restrict__ Wv,
                                                const float* __restrict__ Wo,
                                                u16* __restrict__ xq_bf,
                                                u16* __restrict__ xkv_bf,
                                                u16* __restrict__ wq_t,
                                                u16* __restrict__ wk_t,
                                                u16* __restrict__ wv_t,
                                                u16* __restrict__ wo_t)
{
    __shared__ u16 t[64][72];
    const int tid = threadIdx.x;
    int bid = blockIdx.x;

    if (bid < 8192) {
        const size_t NE = (size_t)4096 * 2048 / 8;
        size_t idx = (size_t)bid * 256 + tid;
        const float* src; u16* dst; size_t off;
        if (idx < NE) { src = Xq;  dst = xq_bf;  off = idx * 8; }
        else          { src = Xkv; dst = xkv_bf; off = (idx - NE) * 8; }
        float4 a = *(const float4*)&src[off];
        float4 b = *(const float4*)&src[off + 4];
        ushort4 r0, r1;
        r0.x = f2bf(a.x); r0.y = f2bf(a.y); r0.z = f2bf(a.z); r0.w = f2bf(a.w);
        r1.x = f2bf(b.x); r1.y = f2bf(b.y); r1.z = f2bf(b.z); r1.w = f2bf(b.w);
        *(ushort4*)&dst[off] = r0;
        *(ushort4*)&dst[off + 4] = r1;
        return;
    }
    bid -= 8192;
    const float* src; u16* dst; int C, gx; bool kperm = false;
    const int R = 2048;
    if (bid < 1024)      { src = Wq; dst = wq_t; C = 2048; gx = 32; }
    else if (bid < 1280) { src = Wk; dst = wk_t; C = 512;  gx = 8;  bid -= 1024; kperm = true; }
    else if (bid < 1536) { src = Wv; dst = wv_t; C = 512;  gx = 8;  bid -= 1280; }
    else                 { src = Wo; dst = wo_t; C = 2048; gx = 32; bid -= 1536; }

    const int r0 = (bid / gx) * 64, c0 = (bid % gx) * 64;
    const int tr = tid >> 4, tc4 = (tid & 15) * 4;
#pragma unroll
    for (int p = 0; p < 4; p++) {
        int r = p * 16 + tr;
        float4 v = *(const float4*)&src[(size_t)(r0 + r) * C + c0 + tc4];
        t[tc4 + 0][r] = f2bf(v.x);
        t[tc4 + 1][r] = f2bf(v.y);
        t[tc4 + 2][r] = f2bf(v.z);
        t[tc4 + 3][r] = f2bf(v.w);
    }
    __syncthreads();
#pragma unroll
    for (int p = 0; p < 4; p++) {
        int cc = p * 16 + tr;
        int rr = c0 + cc;
        if (kperm) {
            int h = rr & 127;
            rr = (rr & ~127) | (h & 15) | (((h >> 6) & 1) << 4)
               | (((h >> 4) & 1) << 5) | (((h >> 5) & 1) << 6);
        }
        ushort4 w = *(const ushort4*)&t[cc][tc4];
        *(ushort4*)&dst[(size_t)rr * R + r0 + tc4] = w;
    }
}

// ---------------------------------------------------------------------------
// 8-phase 256x256 bf16 GEMM mainloop (HK-style schedule, plain HIP).
// ---------------------------------------------------------------------------
#define GPH(c, ks, mh, STAGE, VMW) do {                                        \
    bf16x8 Af[4];                                                              \
    _Pragma("unroll")                                                          \
    for (int mf = 0; mf < 4; mf++)                                             \
        Af[mf] = *(const bf16x8*)&Ab[c][ks][(arow + (mh) * 64 + mf * 16) * 32 + cxs]; \
    if ((mh) == 0) {                                                           \
        _Pragma("unroll")                                                      \
        for (int nf = 0; nf < 4; nf++)                                         \
            Bf[nf] = *(const bf16x8*)&Bb[c][ks][(brow + nf * 16) * 32 + cxs];  \
    }                                                                          \
    STAGE;                                                                     \
    BARRIER;                                                                   \
    asm volatile("s_waitcnt lgkmcnt(0)" ::: "memory");                         \
    __builtin_amdgcn_s_setprio(1);                                             \
    _Pragma("unroll")                                                          \
    for (int mf = 0; mf < 4; mf++)                                             \
        _Pragma("unroll")                                                      \
        for (int nf = 0; nf < 4; nf++)                                         \
            acc[(mh) * 4 + mf][nf] = __builtin_amdgcn_mfma_f32_16x16x32_bf16(  \
                Af[mf], Bf[nf], acc[(mh) * 4 + mf][nf], 0, 0, 0);              \
    __builtin_amdgcn_s_setprio(0);                                             \
    VMW;                                                                       \
    BARRIER;                                                                   \
} while (0)

__device__ __forceinline__ void gemm8_mainloop(const u16* __restrict__ A,
                                               const u16* __restrict__ Bt,
                                               int m0, int n0,
                                               u16 (&Ab)[2][2][256 * 32],
                                               u16 (&Bb)[2][2][256 * 32],
                                               f32x4 (&acc)[8][4])
{
    const int tid = threadIdx.x;
    const int wv = tid >> 6, lane = tid & 63;
    const int l15 = lane & 15, quad = lane >> 4;
    const int wr = wv >> 2, wc = wv & 3;

#pragma unroll
    for (int mf = 0; mf < 8; mf++)
#pragma unroll
        for (int nf = 0; nf < 4; nf++) acc[mf][nf] = (f32x4){0.f, 0.f, 0.f, 0.f};

    auto stageA = [&](int kt, int kh, int c) {
#pragma unroll
        for (int j = 0; j < 2; j++) {
            int q = j * 512 + tid;
            int r = q >> 2;
            int c4 = (q & 3) ^ (r & 3);
            gload16(A + (size_t)(m0 + r) * 2048 + kt * 64 + kh * 32 + c4 * 8,
                    &Ab[c][kh][q * 8]);
        }
    };
    auto stageB = [&](int kt, int kh, int c) {
#pragma unroll
        for (int j = 0; j < 2; j++) {
            int q = j * 512 + tid;
            int r = q >> 2;
            int c4 = (q & 3) ^ (r & 3);
            gload16(Bt + (size_t)(n0 + r) * 2048 + kt * 64 + kh * 32 + c4 * 8,
                    &Bb[c][kh][q * 8]);
        }
    };

    const int arow = wr * 128 + l15;
    const int brow = wc * 64 + l15;
    const int cxs  = (quad ^ (l15 & 3)) * 8;

    stageA(0, 0, 0); stageB(0, 0, 0);
    stageA(0, 1, 0); stageB(0, 1, 0);
    stageA(1, 0, 1); stageB(1, 0, 1);
    VM8;
    BARRIER;

    bf16x8 Bf[4];
    for (int it = 0; it < 15; it++) {
        const int t0 = 2 * it, t1 = 2 * it + 1;
        GPH(0, 0, 0, { stageA(t1, 1, 1); },     VMNONE);
        GPH(0, 0, 1, { stageB(t1, 1, 1); },     VM8);
        GPH(0, 1, 0, { stageA(t0 + 2, 0, 0); }, VMNONE);
        GPH(0, 1, 1, { stageB(t0 + 2, 0, 0); }, VM8);
        GPH(1, 0, 0, { stageA(t0 + 2, 1, 0); }, VMNONE);
        GPH(1, 0, 1, { stageB(t0 + 2, 1, 0); }, VM8);
        GPH(1, 1, 0, { stageA(t1 + 2, 0, 1); }, VMNONE);
        GPH(1, 1, 1, { stageB(t1 + 2, 0, 1); }, VM8);
    }
    GPH(0, 0, 0, { stageA(31, 1, 1); }, VMNONE);
    GPH(0, 0, 1, { stageB(31, 1, 1); }, VM8);
    GPH(0, 1, 0, VMNONE, VMNONE);
    GPH(0, 1, 1, VMNONE, VM4);
    GPH(1, 0, 0, VMNONE, VMNONE);
    GPH(1, 0, 1, VMNONE, VM0);
    GPH(1, 1, 0, VMNONE, VMNONE);
    GPH(1, 1, 1, VMNONE, VMNONE);
}

// Fused QKV + K-RoPE: grid (12, 16) = 192 blocks (XCD-swizzled).
// col tiles: 0-7 q (plain), 8-9 k (rope in epilogue via permuted Wk^T), 10-11 v.
__global__ __launch_bounds__(512, 2) void qkv_gemm8(const u16* __restrict__ Xq,
                                                    const u16* __restrict__ Xkv,
                                                    const u16* __restrict__ Wqt,
                                                    const u16* __restrict__ Wkt,
                                                    const u16* __restrict__ Wvt,
                                                    const int* __restrict__ kvpos,
                                                    u16* __restrict__ qraw,
                                                    u16* __restrict__ kraw,
                                                    u16* __restrict__ vt)
{
    __shared__ __align__(16) u16 Ab[2][2][256 * 32];
    __shared__ __align__(16) u16 Bb[2][2][256 * 32];
    f32x4 acc[8][4];

    const int bid0 = (int)blockIdx.x + 12 * (int)blockIdx.y;
    const int swz  = (bid0 & 7) * 24 + (bid0 >> 3);
    const int cx   = swz % 12;
    const int m0   = (swz / 12) * 256;

    const u16 *A, *Bt; int nb;
    if (cx < 8)       { A = Xq;  Bt = Wqt; nb = cx * 256; }
    else if (cx < 10) { A = Xkv; Bt = Wkt; nb = (cx - 8) * 256; }
    else              { A = Xkv; Bt = Wvt; nb = (cx - 10) * 256; }

    gemm8_mainloop(A, Bt, m0, nb, Ab, Bb, acc);

    const int tid = threadIdx.x;
    const int wv = tid >> 6, lane = tid & 63;
    const int l15 = lane & 15, quad = lane >> 4;
    const int wr = wv >> 2, wc = wv & 3;
    const int row0 = m0 + wr * 128;

    if (cx < 8) {
        // q: plain bf16 write (rope+prescale applied later, in flash)
#pragma unroll
        for (int mf = 0; mf < 8; mf++)
#pragma unroll
            for (int nf = 0; nf < 4; nf++) {
                int col = nb + wc * 64 + nf * 16 + l15;
                int r = row0 + mf * 16 + quad * 4;
#pragma unroll
                for (int reg = 0; reg < 4; reg++)
                    qraw[(size_t)(r + reg) * 2048 + col] = f2bf(acc[mf][nf][reg]);
            }
    } else if (cx < 10) {
        // k with fused RoPE. Wk^T rows were tau^-1-permuted, so acc col j holds
        // true head-col tau(j): h6=nf&1, h5=wc&1, h4=nf>>1, h3..0=l15.
        // => pairs (h, h+64) sit in (nf=2p, nf=2p+1) of the SAME thread.
        const int b = m0 >> 11;
        const int t0r = (m0 & 2047) + wr * 128;
        const int kvh = (nb >> 7) + (wc >> 1);
        const int hb0 = ((wc & 1) << 5) | l15;
#pragma unroll
        for (int pair = 0; pair < 2; pair++) {
            const int h = hb0 | (pair << 4);
            const float inv_ts = expf(-(float)h * 0.14391156831f);
#pragma unroll
            for (int mf = 0; mf < 8; mf++) {
#pragma unroll
                for (int reg = 0; reg < 4; reg++) {
                    int trr = t0r + mf * 16 + quad * 4 + reg;
                    int pos = kvpos[b * 2048 + trr];
                    float s, c;
                    sincosf((float)pos * inv_ts, &s, &c);
                    float x1 = acc[mf][pair * 2 + 0][reg];
                    float x2 = acc[mf][pair * 2 + 1][reg];
                    u16* kp = kraw + ((size_t)(b * 2048 + trr)) * 512 + kvh * 128 + h;
                    kp[0]  = f2bf(x1 * c - x2 * s);
                    kp[64] = f2bf(x2 * c + x1 * s);
                }
            }
        }
    } else {
        const int b = m0 >> 11;
#pragma unroll
        for (int mf = 0; mf < 8; mf++)
#pragma unroll
            for (int nf = 0; nf < 4; nf++) {
                int col = nb + wc * 64 + nf * 16 + l15;
                int tloc = ((row0 & 2047) + mf * 16 + quad * 4);
                ushort4 w4;
                w4.x = f2bf(acc[mf][nf][0]);
                w4.y = f2bf(acc[mf][nf][1]);
                w4.z = f2bf(acc[mf][nf][2]);
                w4.w = f2bf(acc[mf][nf][3]);
                *(ushort4*)&vt[((size_t)(b * 512 + col)) * 2048 + tloc] = w4;
            }
    }
}

// Output projection, 8-phase: grid (8, 16) = 128 blocks (XCD-swizzled).
__global__ __launch_bounds__(512, 2) void oproj_gemm8(const u16* __restrict__ attnb,
                                                      const u16* __restrict__ Wot,
                                                      float* __restrict__ out)
{
    __shared__ __align__(16) u16 Ab[2][2][256 * 32];
    __shared__ __align__(16) u16 Bb[2][2][256 * 32];
    f32x4 acc[8][4];

    const int bid0 = (int)blockIdx.x + 8 * (int)blockIdx.y;
    const int swz  = (bid0 & 7) * 16 + (bid0 >> 3);
    const int n0   = (swz % 8) * 256;
    const int m0   = (swz / 8) * 256;

    gemm8_mainloop(attnb, Wot, m0, n0, Ab, Bb, acc);

    const int tid = threadIdx.x;
    const int wv = tid >> 6, lane = tid & 63;
    const int l15 = lane & 15, quad = lane >> 4;
    const int wr = wv >> 2, wc = wv & 3;
    const int row0 = m0 + wr * 128;
#pragma unroll
    for (int mf = 0; mf < 8; mf++)
#pragma unroll
        for (int nf = 0; nf < 4; nf++) {
            int col = n0 + wc * 64 + nf * 16 + l15;
            int r = row0 + mf * 16 + quad * 4;
#pragma unroll
            for (int reg = 0; reg < 4; reg++)
                out[(size_t)(r + reg) * 2048 + col] = acc[mf][nf][reg];
        }
}

// ---------------------------------------------------------------------------
// Flash attention v6: v5 + Q-RoPE fused at fragment load (thread-local:
// pair (h, h+64) = (kt, kt+2) of the same lane; 16 sincos once per block),
// with QPRESCALE folded into the rotation. rope_bf kernel deleted.
// ---------------------------------------------------------------------------
__global__ __launch_bounds__(512, 4) void flash_attn_v6(const u16* __restrict__ qh,
                                                        const u16* __restrict__ kh,
                                                        const u16* __restrict__ vtg,
                                                        const int* __restrict__ qpos,
                                                        u16* __restrict__ attnb)
{
    __shared__ __align__(16) u16 Ks[2][64 * 128];
    __shared__ __align__(16) u16 Vt[2][128 * 64];
    __shared__ __align__(16) u16 Ps[128 * 64];

    const int yy = blockIdx.y;
    const int qt = (yy < 8) ? (15 - yy) : (yy - 8);   // balanced pairing
    const int bh = blockIdx.x;
    const int b = bh >> 4, n = bh & 15, kvh = n >> 2;
    const int q0 = qt * 128;
    const int tid = threadIdx.x;
    const int wv = tid >> 6, lane = tid & 63;          // wv in 0..7
    const int l15 = lane & 15, quad = lane >> 4;

    const size_t kbase = (size_t)(b * Tdim) * 512 + kvh * 128;
    const size_t vbase = ((size_t)(b * 512 + kvh * 128)) * 2048;
    const int nT = 2 * qt + 2;

    auto stage = [&](int t, int buf) {
        const int s0s = t * 64;
#pragma unroll
        for (int c = 0; c < 2; c++) {
            int j = c * 512 + tid;        // 0..1023
            int s = j >> 4;               // 0..63
            int c8 = (j & 15) ^ (s & 7);
            gload16(kh + kbase + (size_t)(s0s + s) * 512 + c8 * 8,
                    &Ks[buf][(c * 512 + wv * 64) * 8]);
            int h = j >> 3;               // 0..127
            int sb = (j & 7) ^ (h & 7);
            gload16(vtg + vbase + (size_t)h * 2048 + s0s + sb * 8,
                    &Vt[buf][(c * 512 + wv * 64) * 8]);
        }
    };

    stage(0, 0);

    // ---- Q fragments + fused RoPE (overlapped with tile-0 staging) ----
    bf16x8 qfrag[4];
    {
        const size_t qbase = ((size_t)(b * Tdim + q0 + wv * 16)) * 2048 + n * 128;
        float qv[4][8];
#pragma unroll
        for (int kt = 0; kt < 4; kt++) {
            bf16x8 raw = *(const bf16x8*)(qh + qbase + (size_t)l15 * 2048
                                           + kt * 32 + quad * 8);
#pragma unroll
            for (int j = 0; j < 8; j++) qv[kt][j] = (float)raw[j];
        }
        const int pos = qpos[b * Tdim + q0 + wv * 16 + l15];
#pragma unroll
        for (int kt = 0; kt < 2; kt++)
#pragma unroll
            for (int j = 0; j < 8; j++) {
                int h = kt * 32 + quad * 8 + j;     // in [0,64)
                float inv_ts = expf(-(float)h * 0.14391156831f);
                float s, c;
                sincosf((float)pos * inv_ts, &s, &c);
                s *= QPRESCALE; c *= QPRESCALE;
                float x1 = qv[kt][j], x2 = qv[kt + 2][j];
                qv[kt][j]     = x1 * c - x2 * s;
                qv[kt + 2][j] = x2 * c + x1 * s;
            }
#pragma unroll
        for (int kt = 0; kt < 4; kt++) {
            bf16x8 f;
#pragma unroll
            for (int j = 0; j < 8; j++) f[j] = (__bf16)qv[kt][j];
            qfrag[kt] = f;
        }
    }

    f32x4 Oacc[8];
#pragma unroll
    for (int ht = 0; ht < 8; ht++) Oacc[ht] = (f32x4){0.f, 0.f, 0.f, 0.f};
    float mrow = NEG_INF;
    float lrow = 0.f;

    __syncthreads();   // tile 0 staged

    int cur = 0;
    for (int t = 0; t < nT; t++) {
        const int s0 = t * 64;

        if (t + 1 < nT) stage(t + 1, cur ^ 1);

        f32x4 S[4];
#pragma unroll
        for (int nt = 0; nt < 4; nt++) S[nt] = (f32x4){0.f, 0.f, 0.f, 0.f};
#pragma unroll
        for (int kt = 0; kt < 4; kt++) {
            bf16x8 kf[4];
#pragma unroll
            for (int nt = 0; nt < 4; nt++) {
                int s = nt * 16 + l15;
                int cb = (kt * 4 + quad) ^ (s & 7);
                kf[nt] = *(const bf16x8*)&Ks[cur][s * 128 + cb * 8];
            }
#pragma unroll
            for (int nt = 0; nt < 4; nt++)
                S[nt] = __builtin_amdgcn_mfma_f32_16x16x32_bf16(kf[nt], qfrag[kt], S[nt], 0, 0, 0);
        }

        const bool domask = (t >= nT - 2);
        const int m_l = wv * 16 + l15;
        const int mg = q0 + m_l;
        float sv[16];
#pragma unroll
        for (int nt = 0; nt < 4; nt++)
#pragma unroll
            for (int r = 0; r < 4; r++) {
                float vv = S[nt][r];
                if (domask) {
                    int sg = s0 + nt * 16 + quad * 4 + r;
                    if (sg > mg) vv = NEG_INF;
                }
                sv[nt * 4 + r] = vv;
            }
        float mx = quad_reduce_max(tree_max16(sv));
        const bool skip = __all(mx <= mrow + DEFER_THR);
        const float mNew = skip ? mrow : fmaxf(mrow, mx);
#pragma unroll
        for (int i = 0; i < 16; i++)
            sv[i] = __builtin_amdgcn_exp2f(sv[i] - mNew);
#pragma unroll
        for (int nt = 0; nt < 4; nt++) {
            int sb = nt * 2 + (quad >> 1);
            int cb = sb ^ (m_l & 7);
            ushort4 pw;
            pw.x = f2bfn(sv[nt * 4 + 0]);
            pw.y = f2bfn(sv[nt * 4 + 1]);
            pw.z = f2bfn(sv[nt * 4 + 2]);
            pw.w = f2bfn(sv[nt * 4 + 3]);
            *(ushort4*)&Ps[m_l * 64 + cb * 8 + (quad & 1) * 4] = pw;
        }
        {
            float ps = quad_reduce_sum(tree_sum16(sv));
            if (skip) {
                lrow += ps;
            } else {
                float alpha = __builtin_amdgcn_exp2f(mrow - mNew);
                mrow = mNew;
                lrow = lrow * alpha + ps;
                float a0 = __shfl(alpha, quad * 4 + 0);
                float a1 = __shfl(alpha, quad * 4 + 1);
                float a2 = __shfl(alpha, quad * 4 + 2);
                float a3 = __shfl(alpha, quad * 4 + 3);
#pragma unroll
                for (int ht = 0; ht < 8; ht++) {
                    Oacc[ht][0] *= a0;
                    Oacc[ht][1] *= a1;
                    Oacc[ht][2] *= a2;
                    Oacc[ht][3] *= a3;
                }
            }
        }

#pragma unroll
        for (int k2 = 0; k2 < 2; k2++) {
            int cbp = (k2 * 4 + quad) ^ (m_l & 7);
            bf16x8 pf = *(const bf16x8*)&Ps[m_l * 64 + cbp * 8];
#pragma unroll
            for (int ht = 0; ht < 8; ht++) {
                int h = ht * 16 + l15;
                int cb = (k2 * 4 + quad) ^ (h & 7);
                bf16x8 vf = *(const bf16x8*)&Vt[cur][h * 64 + cb * 8];
                Oacc[ht] = __builtin_amdgcn_mfma_f32_16x16x32_bf16(pf, vf, Oacc[ht], 0, 0, 0);
            }
        }

        __syncthreads();
        cur ^= 1;
    }

    {
        f32x4 inv;
#pragma unroll
        for (int r = 0; r < 4; r++)
            inv[r] = 1.0f / __shfl(lrow, quad * 4 + r);
        int mg0 = q0 + wv * 16 + quad * 4;
        u16* dst0 = attnb + ((size_t)(b * Tdim + mg0)) * 2048 + n * 128 + l15;
#pragma unroll
        for (int ht = 0; ht < 8; ht++) {
#pragma unroll
            for (int r = 0; r < 4; r++)
                dst0[(size_t)r * 2048 + ht * 16] = f2bfn(Oacc[ht][r] * inv[r]);
        }
    }
}

extern "C" void kernel_launch(void* const* d_in, const int* in_sizes, int n_in,
                              void* d_out, int out_size, void* d_ws, size_t ws_size,
                              hipStream_t stream) {
    const float* Xq    = (const float*)d_in[0];
    const float* Xkv   = (const float*)d_in[1];
    const int*   qpos  = (const int*)d_in[2];
    const int*   kvpos = (const int*)d_in[3];
    const float* Wq    = (const float*)d_in[4];
    const float* Wk    = (const float*)d_in[5];
    const float* Wv    = (const float*)d_in[6];
    const float* Wo    = (const float*)d_in[7];
    float* out = (float*)d_out;

    char* w = (char*)d_ws;
    u16* xq_bf = (u16*)(w);                    // 16 MB
    u16* xkv_bf= (u16*)(w + (16u << 20));      // 16 MB
    u16* qraw  = (u16*)(w + (32u << 20));      // 16 MB (un-roped; flash ropes)
    u16* kraw  = (u16*)(w + (48u << 20));      //  4 MB (roped in qkv epilogue)
    u16* vt    = (u16*)(w + (52u << 20));      //  4 MB [(b*4+kvh)*128+h][2048]
    u16* wq_t  = (u16*)(w + (56u << 20));      //  8 MB
    u16* wk_t  = (u16*)(w + (64u << 20));      //  2 MB (tau^-1 row-permuted)
    u16* wv_t  = (u16*)(w + (66u << 20));      //  2 MB
    u16* wo_t  = (u16*)(w + (68u << 20));      //  8 MB
    u16* attnb = (u16*)(w);                    // aliases xq_bf (dead by then)

    prep_all<<<10752, 256, 0, stream>>>(Xq, Xkv, Wq, Wk, Wv, Wo,
                                        xq_bf, xkv_bf, wq_t, wk_t, wv_t, wo_t);
    qkv_gemm8<<<dim3(12, 16), 512, 0, stream>>>(xq_bf, xkv_bf, wq_t, wk_t, wv_t,
                                                kvpos, qraw, kraw, vt);
    flash_attn_v6<<<dim3(32, 16), 512, 0, stream>>>(qraw, kraw, vt, qpos, attnb);
    oproj_gemm8<<<dim3(8, 16), 512, 0, stream>>>(attnb, wo_t, out);
}

// Round 7
// 348.956 us; speedup vs baseline: 1.0739x; 1.0739x over previous
//
#include <hip/hip_runtime.h>
#include <hip/hip_bf16.h>
#include <cstdint>
#include <cstddef>

#define Bdim 2
#define Tdim 2048
#define Ddim 2048
#define NHq  16
#define NKV  4
#define HD   128
#define SCALE 0.08838834764831845f
// SCALE * log2(e): folded into q inside flash's Q-rope so softmax runs in exp2 domain
#define QPRESCALE (0.08838834764831845f * 1.4426950408889634f)
#define NEG_INF (-3.0e38f)
// defer-max threshold (log2 domain): e-domain 8 -> 8*log2e ~ 11.5
#define DEFER_THR 11.5f

typedef unsigned short u16;
typedef unsigned int   u32;
typedef __bf16 bf16x8 __attribute__((ext_vector_type(8)));
typedef float  f32x4  __attribute__((ext_vector_type(4)));

__device__ __forceinline__ u16 f2bf(float f) {
    unsigned int u = __float_as_uint(f);
    u += 0x7FFFu + ((u >> 16) & 1u);   // RNE
    return (u16)(u >> 16);
}
__device__ __forceinline__ u16 f2bfn(float f) {
    __bf16 h = (__bf16)f;
    return __builtin_bit_cast(u16, h);
}
__device__ __forceinline__ float bf2f(u16 s) {
    return __uint_as_float(((unsigned int)s) << 16);
}

#if __has_builtin(__builtin_amdgcn_permlane16_swap) && __has_builtin(__builtin_amdgcn_permlane32_swap)
#define HAVE_PERMLANE_SWAP 1
#endif

__device__ __forceinline__ float quad_reduce_max(float v) {
#ifdef HAVE_PERMLANE_SWAP
    auto r = __builtin_amdgcn_permlane16_swap(__float_as_uint(v), __float_as_uint(v), false, false);
    float m = fmaxf(__uint_as_float(r[0]), __uint_as_float(r[1]));
    auto r2 = __builtin_amdgcn_permlane32_swap(__float_as_uint(m), __float_as_uint(m), false, false);
    return fmaxf(__uint_as_float(r2[0]), __uint_as_float(r2[1]));
#else
    v = fmaxf(v, __shfl_xor(v, 16));
    return fmaxf(v, __shfl_xor(v, 32));
#endif
}
__device__ __forceinline__ float quad_reduce_sum(float v) {
#ifdef HAVE_PERMLANE_SWAP
    auto r = __builtin_amdgcn_permlane16_swap(__float_as_uint(v), __float_as_uint(v), false, false);
    float s = __uint_as_float(r[0]) + __uint_as_float(r[1]);
    auto r2 = __builtin_amdgcn_permlane32_swap(__float_as_uint(s), __float_as_uint(s), false, false);
    return __uint_as_float(r2[0]) + __uint_as_float(r2[1]);
#else
    v += __shfl_xor(v, 16);
    return v + __shfl_xor(v, 32);
#endif
}

__device__ __forceinline__ float tree_max16(const float (&s)[16]) {
    float a0 = fmaxf(s[0], s[1]),  a1 = fmaxf(s[2], s[3]);
    float a2 = fmaxf(s[4], s[5]),  a3 = fmaxf(s[6], s[7]);
    float a4 = fmaxf(s[8], s[9]),  a5 = fmaxf(s[10], s[11]);
    float a6 = fmaxf(s[12], s[13]), a7 = fmaxf(s[14], s[15]);
    float b0 = fmaxf(a0, a1), b1 = fmaxf(a2, a3);
    float b2 = fmaxf(a4, a5), b3 = fmaxf(a6, a7);
    return fmaxf(fmaxf(b0, b1), fmaxf(b2, b3));
}
__device__ __forceinline__ float tree_sum16(const float (&s)[16]) {
    float a0 = s[0] + s[1],  a1 = s[2] + s[3];
    float a2 = s[4] + s[5],  a3 = s[6] + s[7];
    float a4 = s[8] + s[9],  a5 = s[10] + s[11];
    float a6 = s[12] + s[13], a7 = s[14] + s[15];
    float b0 = a0 + a1, b1 = a2 + a3, b2 = a4 + a5, b3 = a6 + a7;
    return (b0 + b1) + (b2 + b3);
}

// async global->LDS, 16B per lane. LDS dest is wave-uniform base + lane*16.
typedef __attribute__((address_space(1))) const u32 gbl_u32;
typedef __attribute__((address_space(3))) u32 lds_u32;
__device__ __forceinline__ void gload16(const void* g, void* l) {
    __builtin_amdgcn_global_load_lds((gbl_u32*)(uintptr_t)g, (lds_u32*)(uintptr_t)l, 16, 0, 0);
}

#define VM8 asm volatile("s_waitcnt vmcnt(8)" ::: "memory")
#define VM4 asm volatile("s_waitcnt vmcnt(4)" ::: "memory")
#define VM0 asm volatile("s_waitcnt vmcnt(0)" ::: "memory")
#define VMNONE ((void)0)
#define BARRIER do { asm volatile("" ::: "memory"); __builtin_amdgcn_s_barrier(); asm volatile("" ::: "memory"); } while (0)

// ---------------------------------------------------------------------------
// prep_all: ONE kernel for all input conversion (replaces cvt_x + 4x cvt_w_t).
// blocks [0,8192):       fp32->bf16 copy of Xq,Xkv (8 elems/thread)
// blocks [8192,10752):   W[R][C] -> bf16 W^T[C][R] 64x64 tiles
// (round-6's Wk row permutation REVERTED — K-rope fusion in the GEMM epilogue
//  caused 7x HBM write amplification; k is roped by rope_k instead.)
// ---------------------------------------------------------------------------
__global__ __launch_bounds__(256) void prep_all(const float* __restrict__ Xq,
                                                const float* __restrict__ Xkv,
                                                const float* __restrict__ Wq,
                                                const float* __restrict__ Wk,
                                                const float* __restrict__ Wv,
                                                const float* __restrict__ Wo,
                                                u16* __restrict__ xq_bf,
                                                u16* __restrict__ xkv_bf,
                                                u16* __restrict__ wq_t,
                                                u16* __restrict__ wk_t,
                                                u16* __restrict__ wv_t,
                                                u16* __restrict__ wo_t)
{
    __shared__ u16 t[64][72];
    const int tid = threadIdx.x;
    int bid = blockIdx.x;

    if (bid < 8192) {
        const size_t NE = (size_t)4096 * 2048 / 8;
        size_t idx = (size_t)bid * 256 + tid;
        const float* src; u16* dst; size_t off;
        if (idx < NE) { src = Xq;  dst = xq_bf;  off = idx * 8; }
        else          { src = Xkv; dst = xkv_bf; off = (idx - NE) * 8; }
        float4 a = *(const float4*)&src[off];
        float4 b = *(const float4*)&src[off + 4];
        ushort4 r0, r1;
        r0.x = f2bf(a.x); r0.y = f2bf(a.y); r0.z = f2bf(a.z); r0.w = f2bf(a.w);
        r1.x = f2bf(b.x); r1.y = f2bf(b.y); r1.z = f2bf(b.z); r1.w = f2bf(b.w);
        *(ushort4*)&dst[off] = r0;
        *(ushort4*)&dst[off + 4] = r1;
        return;
    }
    bid -= 8192;
    const float* src; u16* dst; int C, gx;
    const int R = 2048;
    if (bid < 1024)      { src = Wq; dst = wq_t; C = 2048; gx = 32; }
    else if (bid < 1280) { src = Wk; dst = wk_t; C = 512;  gx = 8;  bid -= 1024; }
    else if (bid < 1536) { src = Wv; dst = wv_t; C = 512;  gx = 8;  bid -= 1280; }
    else                 { src = Wo; dst = wo_t; C = 2048; gx = 32; bid -= 1536; }

    const int r0 = (bid / gx) * 64, c0 = (bid % gx) * 64;
    const int tr = tid >> 4, tc4 = (tid & 15) * 4;
#pragma unroll
    for (int p = 0; p < 4; p++) {
        int r = p * 16 + tr;
        float4 v = *(const float4*)&src[(size_t)(r0 + r) * C + c0 + tc4];
        t[tc4 + 0][r] = f2bf(v.x);
        t[tc4 + 1][r] = f2bf(v.y);
        t[tc4 + 2][r] = f2bf(v.z);
        t[tc4 + 3][r] = f2bf(v.w);
    }
    __syncthreads();
#pragma unroll
    for (int p = 0; p < 4; p++) {
        int cc = p * 16 + tr;
        ushort4 w = *(const ushort4*)&t[cc][tc4];
        *(ushort4*)&dst[(size_t)(c0 + cc) * R + r0 + tc4] = w;
    }
}

// ---------------------------------------------------------------------------
// In-place RoPE on bf16 k only (q is roped inside flash_attn).
// kraw layout: [(b*T+t)*4 + kvh][128]. 262144 threads, grid 1024.
// ---------------------------------------------------------------------------
__global__ __launch_bounds__(256) void rope_k(u16* __restrict__ k,
                                              const int* __restrict__ kvpos)
{
    int idx = blockIdx.x * 256 + threadIdx.x;
    int rn = idx >> 4;
    int h4 = (idx & 15) * 4;
    int pos = kvpos[rn >> 2];
    u16* base = k + (size_t)rn * HD;
    ushort4 a = *(const ushort4*)&base[h4];
    ushort4 bvec = *(const ushort4*)&base[h4 + 64];
    u16 av[4] = {a.x, a.y, a.z, a.w};
    u16 bv[4] = {bvec.x, bvec.y, bvec.z, bvec.w};
#pragma unroll
    for (int j = 0; j < 4; j++) {
        float inv_ts = expf(-(float)(h4 + j) * 0.14391156831f);
        float ang = (float)pos * inv_ts;
        float s, c;
        sincosf(ang, &s, &c);
        float x1 = bf2f(av[j]), x2 = bf2f(bv[j]);
        av[j] = f2bf(x1 * c - x2 * s);
        bv[j] = f2bf(x2 * c + x1 * s);
    }
    ushort4 ra, rb;
    ra.x = av[0]; ra.y = av[1]; ra.z = av[2]; ra.w = av[3];
    rb.x = bv[0]; rb.y = bv[1]; rb.z = bv[2]; rb.w = bv[3];
    *(ushort4*)&base[h4] = ra;
    *(ushort4*)&base[h4 + 64] = rb;
}

// ---------------------------------------------------------------------------
// 8-phase 256x256 bf16 GEMM mainloop (HK-style schedule, plain HIP).
// ---------------------------------------------------------------------------
#define GPH(c, ks, mh, STAGE, VMW) do {                                        \
    bf16x8 Af[4];                                                              \
    _Pragma("unroll")                                                          \
    for (int mf = 0; mf < 4; mf++)                                             \
        Af[mf] = *(const bf16x8*)&Ab[c][ks][(arow + (mh) * 64 + mf * 16) * 32 + cxs]; \
    if ((mh) == 0) {                                                           \
        _Pragma("unroll")                                                      \
        for (int nf = 0; nf < 4; nf++)                                         \
            Bf[nf] = *(const bf16x8*)&Bb[c][ks][(brow + nf * 16) * 32 + cxs];  \
    }                                                                          \
    STAGE;                                                                     \
    BARRIER;                                                                   \
    asm volatile("s_waitcnt lgkmcnt(0)" ::: "memory");                         \
    __builtin_amdgcn_s_setprio(1);                                             \
    _Pragma("unroll")                                                          \
    for (int mf = 0; mf < 4; mf++)                                             \
        _Pragma("unroll")                                                      \
        for (int nf = 0; nf < 4; nf++)                                         \
            acc[(mh) * 4 + mf][nf] = __builtin_amdgcn_mfma_f32_16x16x32_bf16(  \
                Af[mf], Bf[nf], acc[(mh) * 4 + mf][nf], 0, 0, 0);              \
    __builtin_amdgcn_s_setprio(0);                                             \
    VMW;                                                                       \
    BARRIER;                                                                   \
} while (0)

__device__ __forceinline__ void gemm8_mainloop(const u16* __restrict__ A,
                                               const u16* __restrict__ Bt,
                                               int m0, int n0,
                                               u16 (&Ab)[2][2][256 * 32],
                                               u16 (&Bb)[2][2][256 * 32],
                                               f32x4 (&acc)[8][4])
{
    const int tid = threadIdx.x;
    const int wv = tid >> 6, lane = tid & 63;
    const int l15 = lane & 15, quad = lane >> 4;
    const int wr = wv >> 2, wc = wv & 3;

#pragma unroll
    for (int mf = 0; mf < 8; mf++)
#pragma unroll
        for (int nf = 0; nf < 4; nf++) acc[mf][nf] = (f32x4){0.f, 0.f, 0.f, 0.f};

    auto stageA = [&](int kt, int kh, int c) {
#pragma unroll
        for (int j = 0; j < 2; j++) {
            int q = j * 512 + tid;
            int r = q >> 2;
            int c4 = (q & 3) ^ (r & 3);
            gload16(A + (size_t)(m0 + r) * 2048 + kt * 64 + kh * 32 + c4 * 8,
                    &Ab[c][kh][q * 8]);
        }
    };
    auto stageB = [&](int kt, int kh, int c) {
#pragma unroll
        for (int j = 0; j < 2; j++) {
            int q = j * 512 + tid;
            int r = q >> 2;
            int c4 = (q & 3) ^ (r & 3);
            gload16(Bt + (size_t)(n0 + r) * 2048 + kt * 64 + kh * 32 + c4 * 8,
                    &Bb[c][kh][q * 8]);
        }
    };

    const int arow = wr * 128 + l15;
    const int brow = wc * 64 + l15;
    const int cxs  = (quad ^ (l15 & 3)) * 8;

    stageA(0, 0, 0); stageB(0, 0, 0);
    stageA(0, 1, 0); stageB(0, 1, 0);
    stageA(1, 0, 1); stageB(1, 0, 1);
    VM8;
    BARRIER;

    bf16x8 Bf[4];
    for (int it = 0; it < 15; it++) {
        const int t0 = 2 * it, t1 = 2 * it + 1;
        GPH(0, 0, 0, { stageA(t1, 1, 1); },     VMNONE);
        GPH(0, 0, 1, { stageB(t1, 1, 1); },     VM8);
        GPH(0, 1, 0, { stageA(t0 + 2, 0, 0); }, VMNONE);
        GPH(0, 1, 1, { stageB(t0 + 2, 0, 0); }, VM8);
        GPH(1, 0, 0, { stageA(t0 + 2, 1, 0); }, VMNONE);
        GPH(1, 0, 1, { stageB(t0 + 2, 1, 0); }, VM8);
        GPH(1, 1, 0, { stageA(t1 + 2, 0, 1); }, VMNONE);
        GPH(1, 1, 1, { stageB(t1 + 2, 0, 1); }, VM8);
    }
    GPH(0, 0, 0, { stageA(31, 1, 1); }, VMNONE);
    GPH(0, 0, 1, { stageB(31, 1, 1); }, VM8);
    GPH(0, 1, 0, VMNONE, VMNONE);
    GPH(0, 1, 1, VMNONE, VM4);
    GPH(1, 0, 0, VMNONE, VMNONE);
    GPH(1, 0, 1, VMNONE, VM0);
    GPH(1, 1, 0, VMNONE, VMNONE);
    GPH(1, 1, 1, VMNONE, VMNONE);
}

// Fused QKV: grid (12, 16) = 192 blocks (XCD-swizzled).
// col tiles: 0-7 q, 8-9 k (un-roped; rope_k follows), 10-11 v.
__global__ __launch_bounds__(512, 2) void qkv_gemm8(const u16* __restrict__ Xq,
                                                    const u16* __restrict__ Xkv,
                                                    const u16* __restrict__ Wqt,
                                                    const u16* __restrict__ Wkt,
                                                    const u16* __restrict__ Wvt,
                                                    u16* __restrict__ qraw,
                                                    u16* __restrict__ kraw,
                                                    u16* __restrict__ vt)
{
    __shared__ __align__(16) u16 Ab[2][2][256 * 32];
    __shared__ __align__(16) u16 Bb[2][2][256 * 32];
    f32x4 acc[8][4];

    const int bid0 = (int)blockIdx.x + 12 * (int)blockIdx.y;
    const int swz  = (bid0 & 7) * 24 + (bid0 >> 3);
    const int cx   = swz % 12;
    const int m0   = (swz / 12) * 256;

    const u16 *A, *Bt; int nb;
    if (cx < 8)       { A = Xq;  Bt = Wqt; nb = cx * 256; }
    else if (cx < 10) { A = Xkv; Bt = Wkt; nb = (cx - 8) * 256; }
    else              { A = Xkv; Bt = Wvt; nb = (cx - 10) * 256; }

    gemm8_mainloop(A, Bt, m0, nb, Ab, Bb, acc);

    const int tid = threadIdx.x;
    const int wv = tid >> 6, lane = tid & 63;
    const int l15 = lane & 15, quad = lane >> 4;
    const int wr = wv >> 2, wc = wv & 3;
    const int row0 = m0 + wr * 128;

    if (cx < 10) {
        u16* out; int ldw;
        if (cx < 8) { out = qraw; ldw = 2048; }
        else        { out = kraw; ldw = 512; }
#pragma unroll
        for (int mf = 0; mf < 8; mf++)
#pragma unroll
            for (int nf = 0; nf < 4; nf++) {
                int col = nb + wc * 64 + nf * 16 + l15;
                int r = row0 + mf * 16 + quad * 4;
#pragma unroll
                for (int reg = 0; reg < 4; reg++)
                    out[(size_t)(r + reg) * ldw + col] = f2bf(acc[mf][nf][reg]);
            }
    } else {
        const int b = m0 >> 11;
#pragma unroll
        for (int mf = 0; mf < 8; mf++)
#pragma unroll
            for (int nf = 0; nf < 4; nf++) {
                int col = nb + wc * 64 + nf * 16 + l15;
                int tloc = ((row0 & 2047) + mf * 16 + quad * 4);
                ushort4 w4;
                w4.x = f2bf(acc[mf][nf][0]);
                w4.y = f2bf(acc[mf][nf][1]);
                w4.z = f2bf(acc[mf][nf][2]);
                w4.w = f2bf(acc[mf][nf][3]);
                *(ushort4*)&vt[((size_t)(b * 512 + col)) * 2048 + tloc] = w4;
            }
    }
}

// Output projection, 8-phase: grid (8, 16) = 128 blocks (XCD-swizzled).
__global__ __launch_bounds__(512, 2) void oproj_gemm8(const u16* __restrict__ attnb,
                                                      const u16* __restrict__ Wot,
                                                      float* __restrict__ out)
{
    __shared__ __align__(16) u16 Ab[2][2][256 * 32];
    __shared__ __align__(16) u16 Bb[2][2][256 * 32];
    f32x4 acc[8][4];

    const int bid0 = (int)blockIdx.x + 8 * (int)blockIdx.y;
    const int swz  = (bid0 & 7) * 16 + (bid0 >> 3);
    const int n0   = (swz % 8) * 256;
    const int m0   = (swz / 8) * 256;

    gemm8_mainloop(attnb, Wot, m0, n0, Ab, Bb, acc);

    const int tid = threadIdx.x;
    const int wv = tid >> 6, lane = tid & 63;
    const int l15 = lane & 15, quad = lane >> 4;
    const int wr = wv >> 2, wc = wv & 3;
    const int row0 = m0 + wr * 128;
#pragma unroll
    for (int mf = 0; mf < 8; mf++)
#pragma unroll
        for (int nf = 0; nf < 4; nf++) {
            int col = n0 + wc * 64 + nf * 16 + l15;
            int r = row0 + mf * 16 + quad * 4;
#pragma unroll
            for (int reg = 0; reg < 4; reg++)
                out[(size_t)(r + reg) * 2048 + col] = acc[mf][nf][reg];
        }
}

// ---------------------------------------------------------------------------
// Flash attention v6: BQ=128 over 8 waves (16 rows each), BKV=64, dbuf K/V,
// Q-RoPE fused at fragment load (thread-local pairs (kt, kt+2); QPRESCALE
// folded into the rotation).
// ---------------------------------------------------------------------------
__global__ __launch_bounds__(512, 4) void flash_attn_v6(const u16* __restrict__ qh,
                                                        const u16* __restrict__ kh,
                                                        const u16* __restrict__ vtg,
                                                        const int* __restrict__ qpos,
                                                        u16* __restrict__ attnb)
{
    __shared__ __align__(16) u16 Ks[2][64 * 128];
    __shared__ __align__(16) u16 Vt[2][128 * 64];
    __shared__ __align__(16) u16 Ps[128 * 64];

    const int yy = blockIdx.y;
    const int qt = (yy < 8) ? (15 - yy) : (yy - 8);   // balanced pairing
    const int bh = blockIdx.x;
    const int b = bh >> 4, n = bh & 15, kvh = n >> 2;
    const int q0 = qt * 128;
    const int tid = threadIdx.x;
    const int wv = tid >> 6, lane = tid & 63;          // wv in 0..7
    const int l15 = lane & 15, quad = lane >> 4;

    const size_t kbase = (size_t)(b * Tdim) * 512 + kvh * 128;
    const size_t vbase = ((size_t)(b * 512 + kvh * 128)) * 2048;
    const int nT = 2 * qt + 2;

    auto stage = [&](int t, int buf) {
        const int s0s = t * 64;
#pragma unroll
        for (int c = 0; c < 2; c++) {
            int j = c * 512 + tid;        // 0..1023
            int s = j >> 4;               // 0..63
            int c8 = (j & 15) ^ (s & 7);
            gload16(kh + kbase + (size_t)(s0s + s) * 512 + c8 * 8,
                    &Ks[buf][(c * 512 + wv * 64) * 8]);
            int h = j >> 3;               // 0..127
            int sb = (j & 7) ^ (h & 7);
            gload16(vtg + vbase + (size_t)h * 2048 + s0s + sb * 8,
                    &Vt[buf][(c * 512 + wv * 64) * 8]);
        }
    };

    stage(0, 0);

    // ---- Q fragments + fused RoPE (overlapped with tile-0 staging) ----
    bf16x8 qfrag[4];
    {
        const size_t qbase = ((size_t)(b * Tdim + q0 + wv * 16)) * 2048 + n * 128;
        float qv[4][8];
#pragma unroll
        for (int kt = 0; kt < 4; kt++) {
            bf16x8 raw = *(const bf16x8*)(qh + qbase + (size_t)l15 * 2048
                                           + kt * 32 + quad * 8);
#pragma unroll
            for (int j = 0; j < 8; j++) qv[kt][j] = (float)raw[j];
        }
        const int pos = qpos[b * Tdim + q0 + wv * 16 + l15];
#pragma unroll
        for (int kt = 0; kt < 2; kt++)
#pragma unroll
            for (int j = 0; j < 8; j++) {
                int h = kt * 32 + quad * 8 + j;     // in [0,64)
                float inv_ts = expf(-(float)h * 0.14391156831f);
                float s, c;
                sincosf((float)pos * inv_ts, &s, &c);
                s *= QPRESCALE; c *= QPRESCALE;
                float x1 = qv[kt][j], x2 = qv[kt + 2][j];
                qv[kt][j]     = x1 * c - x2 * s;
                qv[kt + 2][j] = x2 * c + x1 * s;
            }
#pragma unroll
        for (int kt = 0; kt < 4; kt++) {
            bf16x8 f;
#pragma unroll
            for (int j = 0; j < 8; j++) f[j] = (__bf16)qv[kt][j];
            qfrag[kt] = f;
        }
    }

    f32x4 Oacc[8];
#pragma unroll
    for (int ht = 0; ht < 8; ht++) Oacc[ht] = (f32x4){0.f, 0.f, 0.f, 0.f};
    float mrow = NEG_INF;
    float lrow = 0.f;

    __syncthreads();   // tile 0 staged

    int cur = 0;
    for (int t = 0; t < nT; t++) {
        const int s0 = t * 64;

        if (t + 1 < nT) stage(t + 1, cur ^ 1);

        f32x4 S[4];
#pragma unroll
        for (int nt = 0; nt < 4; nt++) S[nt] = (f32x4){0.f, 0.f, 0.f, 0.f};
#pragma unroll
        for (int kt = 0; kt < 4; kt++) {
            bf16x8 kf[4];
#pragma unroll
            for (int nt = 0; nt < 4; nt++) {
                int s = nt * 16 + l15;
                int cb = (kt * 4 + quad) ^ (s & 7);
                kf[nt] = *(const bf16x8*)&Ks[cur][s * 128 + cb * 8];
            }
#pragma unroll
            for (int nt = 0; nt < 4; nt++)
                S[nt] = __builtin_amdgcn_mfma_f32_16x16x32_bf16(kf[nt], qfrag[kt], S[nt], 0, 0, 0);
        }

        const bool domask = (t >= nT - 2);
        const int m_l = wv * 16 + l15;
        const int mg = q0 + m_l;
        float sv[16];
#pragma unroll
        for (int nt = 0; nt < 4; nt++)
#pragma unroll
            for (int r = 0; r < 4; r++) {
                float vv = S[nt][r];
                if (domask) {
                    int sg = s0 + nt * 16 + quad * 4 + r;
                    if (sg > mg) vv = NEG_INF;
                }
                sv[nt * 4 + r] = vv;
            }
        float mx = quad_reduce_max(tree_max16(sv));
        const bool skip = __all(mx <= mrow + DEFER_THR);
        const float mNew = skip ? mrow : fmaxf(mrow, mx);
#pragma unroll
        for (int i = 0; i < 16; i++)
            sv[i] = __builtin_amdgcn_exp2f(sv[i] - mNew);
#pragma unroll
        for (int nt = 0; nt < 4; nt++) {
            int sb = nt * 2 + (quad >> 1);
            int cb = sb ^ (m_l & 7);
            ushort4 pw;
            pw.x = f2bfn(sv[nt * 4 + 0]);
            pw.y = f2bfn(sv[nt * 4 + 1]);
            pw.z = f2bfn(sv[nt * 4 + 2]);
            pw.w = f2bfn(sv[nt * 4 + 3]);
            *(ushort4*)&Ps[m_l * 64 + cb * 8 + (quad & 1) * 4] = pw;
        }
        {
            float ps = quad_reduce_sum(tree_sum16(sv));
            if (skip) {
                lrow += ps;
            } else {
                float alpha = __builtin_amdgcn_exp2f(mrow - mNew);
                mrow = mNew;
                lrow = lrow * alpha + ps;
                float a0 = __shfl(alpha, quad * 4 + 0);
                float a1 = __shfl(alpha, quad * 4 + 1);
                float a2 = __shfl(alpha, quad * 4 + 2);
                float a3 = __shfl(alpha, quad * 4 + 3);
#pragma unroll
                for (int ht = 0; ht < 8; ht++) {
                    Oacc[ht][0] *= a0;
                    Oacc[ht][1] *= a1;
                    Oacc[ht][2] *= a2;
                    Oacc[ht][3] *= a3;
                }
            }
        }

#pragma unroll
        for (int k2 = 0; k2 < 2; k2++) {
            int cbp = (k2 * 4 + quad) ^ (m_l & 7);
            bf16x8 pf = *(const bf16x8*)&Ps[m_l * 64 + cbp * 8];
#pragma unroll
            for (int ht = 0; ht < 8; ht++) {
                int h = ht * 16 + l15;
                int cb = (k2 * 4 + quad) ^ (h & 7);
                bf16x8 vf = *(const bf16x8*)&Vt[cur][h * 64 + cb * 8];
                Oacc[ht] = __builtin_amdgcn_mfma_f32_16x16x32_bf16(pf, vf, Oacc[ht], 0, 0, 0);
            }
        }

        __syncthreads();
        cur ^= 1;
    }

    {
        f32x4 inv;
#pragma unroll
        for (int r = 0; r < 4; r++)
            inv[r] = 1.0f / __shfl(lrow, quad * 4 + r);
        int mg0 = q0 + wv * 16 + quad * 4;
        u16* dst0 = attnb + ((size_t)(b * Tdim + mg0)) * 2048 + n * 128 + l15;
#pragma unroll
        for (int ht = 0; ht < 8; ht++) {
#pragma unroll
            for (int r = 0; r < 4; r++)
                dst0[(size_t)r * 2048 + ht * 16] = f2bfn(Oacc[ht][r] * inv[r]);
        }
    }
}

extern "C" void kernel_launch(void* const* d_in, const int* in_sizes, int n_in,
                              void* d_out, int out_size, void* d_ws, size_t ws_size,
                              hipStream_t stream) {
    const float* Xq    = (const float*)d_in[0];
    const float* Xkv   = (const float*)d_in[1];
    const int*   qpos  = (const int*)d_in[2];
    const int*   kvpos = (const int*)d_in[3];
    const float* Wq    = (const float*)d_in[4];
    const float* Wk    = (const float*)d_in[5];
    const float* Wv    = (const float*)d_in[6];
    const float* Wo    = (const float*)d_in[7];
    float* out = (float*)d_out;

    char* w = (char*)d_ws;
    u16* xq_bf = (u16*)(w);                    // 16 MB
    u16* xkv_bf= (u16*)(w + (16u << 20));      // 16 MB
    u16* qraw  = (u16*)(w + (32u << 20));      // 16 MB (un-roped; flash ropes)
    u16* kraw  = (u16*)(w + (48u << 20));      //  4 MB (roped in place by rope_k)
    u16* vt    = (u16*)(w + (52u << 20));      //  4 MB [(b*4+kvh)*128+h][2048]
    u16* wq_t  = (u16*)(w + (56u << 20));      //  8 MB
    u16* wk_t  = (u16*)(w + (64u << 20));      //  2 MB
    u16* wv_t  = (u16*)(w + (66u << 20));      //  2 MB
    u16* wo_t  = (u16*)(w + (68u << 20));      //  8 MB
    u16* attnb = (u16*)(w);                    // aliases xq_bf (dead by then)

    prep_all<<<10752, 256, 0, stream>>>(Xq, Xkv, Wq, Wk, Wv, Wo,
                                        xq_bf, xkv_bf, wq_t, wk_t, wv_t, wo_t);
    qkv_gemm8<<<dim3(12, 16), 512, 0, stream>>>(xq_bf, xkv_bf, wq_t, wk_t, wv_t,
                                                qraw, kraw, vt);
    rope_k<<<1024, 256, 0, stream>>>(kraw, kvpos);
    flash_attn_v6<<<dim3(32, 16), 512, 0, stream>>>(qraw, kraw, vt, qpos, attnb);
    oproj_gemm8<<<dim3(8, 16), 512, 0, stream>>>(attnb, wo_t, out);
}

// Round 8
// 308.799 us; speedup vs baseline: 1.2135x; 1.1300x over previous
//
#include <hip/hip_runtime.h>
#include <hip/hip_bf16.h>
#include <cstdint>
#include <cstddef>

#define Bdim 2
#define Tdim 2048
#define Ddim 2048
#define NHq  16
#define NKV  4
#define HD   128
#define SCALE 0.08838834764831845f
// SCALE * log2(e): folded into q inside flash's Q-rope so softmax runs in exp2 domain
#define QPRESCALE (0.08838834764831845f * 1.4426950408889634f)
#define NEG_INF (-3.0e38f)
// defer-max threshold (log2 domain): e-domain 8 -> 8*log2e ~ 11.5
#define DEFER_THR 11.5f
// ln(10000)/64 in log2 units: log2(10000)/64
#define ROPE_L2 0.20762051f
// 1/(2*pi)
#define INV_2PI 0.15915494f

typedef unsigned short u16;
typedef unsigned int   u32;
typedef __bf16 bf16x8 __attribute__((ext_vector_type(8)));
typedef float  f32x4  __attribute__((ext_vector_type(4)));

__device__ __forceinline__ u16 f2bf(float f) {
    unsigned int u = __float_as_uint(f);
    u += 0x7FFFu + ((u >> 16) & 1u);   // RNE
    return (u16)(u >> 16);
}
__device__ __forceinline__ u16 f2bfn(float f) {
    __bf16 h = (__bf16)f;
    return __builtin_bit_cast(u16, h);
}
__device__ __forceinline__ float bf2f(u16 s) {
    return __uint_as_float(((unsigned int)s) << 16);
}

// hardware sin/cos: v_sin_f32/v_cos_f32 take REVOLUTIONS; fract first for range.
// rev_scale = exp2(-h*log2(1e4)/64) / (2*pi); error ~1e-4 rad, far below bf16 rounding.
__device__ __forceinline__ void hw_sincos_rev(float rev, float* s, float* c) {
    rev -= floorf(rev);
    *s = __builtin_amdgcn_sinf(rev);
    *c = __builtin_amdgcn_cosf(rev);
}

#if __has_builtin(__builtin_amdgcn_permlane16_swap) && __has_builtin(__builtin_amdgcn_permlane32_swap)
#define HAVE_PERMLANE_SWAP 1
#endif

__device__ __forceinline__ float quad_reduce_max(float v) {
#ifdef HAVE_PERMLANE_SWAP
    auto r = __builtin_amdgcn_permlane16_swap(__float_as_uint(v), __float_as_uint(v), false, false);
    float m = fmaxf(__uint_as_float(r[0]), __uint_as_float(r[1]));
    auto r2 = __builtin_amdgcn_permlane32_swap(__float_as_uint(m), __float_as_uint(m), false, false);
    return fmaxf(__uint_as_float(r2[0]), __uint_as_float(r2[1]));
#else
    v = fmaxf(v, __shfl_xor(v, 16));
    return fmaxf(v, __shfl_xor(v, 32));
#endif
}
__device__ __forceinline__ float quad_reduce_sum(float v) {
#ifdef HAVE_PERMLANE_SWAP
    auto r = __builtin_amdgcn_permlane16_swap(__float_as_uint(v), __float_as_uint(v), false, false);
    float s = __uint_as_float(r[0]) + __uint_as_float(r[1]);
    auto r2 = __builtin_amdgcn_permlane32_swap(__float_as_uint(s), __float_as_uint(s), false, false);
    return __uint_as_float(r2[0]) + __uint_as_float(r2[1]);
#else
    v += __shfl_xor(v, 16);
    return v + __shfl_xor(v, 32);
#endif
}

__device__ __forceinline__ float tree_max16(const float (&s)[16]) {
    float a0 = fmaxf(s[0], s[1]),  a1 = fmaxf(s[2], s[3]);
    float a2 = fmaxf(s[4], s[5]),  a3 = fmaxf(s[6], s[7]);
    float a4 = fmaxf(s[8], s[9]),  a5 = fmaxf(s[10], s[11]);
    float a6 = fmaxf(s[12], s[13]), a7 = fmaxf(s[14], s[15]);
    float b0 = fmaxf(a0, a1), b1 = fmaxf(a2, a3);
    float b2 = fmaxf(a4, a5), b3 = fmaxf(a6, a7);
    return fmaxf(fmaxf(b0, b1), fmaxf(b2, b3));
}
__device__ __forceinline__ float tree_sum16(const float (&s)[16]) {
    float a0 = s[0] + s[1],  a1 = s[2] + s[3];
    float a2 = s[4] + s[5],  a3 = s[6] + s[7];
    float a4 = s[8] + s[9],  a5 = s[10] + s[11];
    float a6 = s[12] + s[13], a7 = s[14] + s[15];
    float b0 = a0 + a1, b1 = a2 + a3, b2 = a4 + a5, b3 = a6 + a7;
    return (b0 + b1) + (b2 + b3);
}

// async global->LDS, 16B per lane. LDS dest is wave-uniform base + lane*16.
typedef __attribute__((address_space(1))) const u32 gbl_u32;
typedef __attribute__((address_space(3))) u32 lds_u32;
__device__ __forceinline__ void gload16(const void* g, void* l) {
    __builtin_amdgcn_global_load_lds((gbl_u32*)(uintptr_t)g, (lds_u32*)(uintptr_t)l, 16, 0, 0);
}

#define VM8 asm volatile("s_waitcnt vmcnt(8)" ::: "memory")
#define VM6 asm volatile("s_waitcnt vmcnt(6)" ::: "memory")
#define VM4 asm volatile("s_waitcnt vmcnt(4)" ::: "memory")
#define VM3 asm volatile("s_waitcnt vmcnt(3)" ::: "memory")
#define VM0 asm volatile("s_waitcnt vmcnt(0)" ::: "memory")
#define VMNONE ((void)0)
#define BARRIER do { asm volatile("" ::: "memory"); __builtin_amdgcn_s_barrier(); asm volatile("" ::: "memory"); } while (0)

// ---------------------------------------------------------------------------
// prep_all: ONE kernel for all input conversion.
// blocks [0,8192):       fp32->bf16 copy of Xq,Xkv (8 elems/thread)
// blocks [8192,10752):   W[R][C] -> bf16 W^T[C][R] 64x64 tiles
// ---------------------------------------------------------------------------
__global__ __launch_bounds__(256) void prep_all(const float* __restrict__ Xq,
                                                const float* __restrict__ Xkv,
                                                const float* __restrict__ Wq,
                                                const float* __restrict__ Wk,
                                                const float* __restrict__ Wv,
                                                const float* __restrict__ Wo,
                                                u16* __restrict__ xq_bf,
                                                u16* __restrict__ xkv_bf,
                                                u16* __restrict__ wq_t,
                                                u16* __restrict__ wk_t,
                                                u16* __restrict__ wv_t,
                                                u16* __restrict__ wo_t)
{
    __shared__ u16 t[64][72];
    const int tid = threadIdx.x;
    int bid = blockIdx.x;

    if (bid < 8192) {
        const size_t NE = (size_t)4096 * 2048 / 8;
        size_t idx = (size_t)bid * 256 + tid;
        const float* src; u16* dst; size_t off;
        if (idx < NE) { src = Xq;  dst = xq_bf;  off = idx * 8; }
        else          { src = Xkv; dst = xkv_bf; off = (idx - NE) * 8; }
        float4 a = *(const float4*)&src[off];
        float4 b = *(const float4*)&src[off + 4];
        ushort4 r0, r1;
        r0.x = f2bf(a.x); r0.y = f2bf(a.y); r0.z = f2bf(a.z); r0.w = f2bf(a.w);
        r1.x = f2bf(b.x); r1.y = f2bf(b.y); r1.z = f2bf(b.z); r1.w = f2bf(b.w);
        *(ushort4*)&dst[off] = r0;
        *(ushort4*)&dst[off + 4] = r1;
        return;
    }
    bid -= 8192;
    const float* src; u16* dst; int C, gx;
    const int R = 2048;
    if (bid < 1024)      { src = Wq; dst = wq_t; C = 2048; gx = 32; }
    else if (bid < 1280) { src = Wk; dst = wk_t; C = 512;  gx = 8;  bid -= 1024; }
    else if (bid < 1536) { src = Wv; dst = wv_t; C = 512;  gx = 8;  bid -= 1280; }
    else                 { src = Wo; dst = wo_t; C = 2048; gx = 32; bid -= 1536; }

    const int r0 = (bid / gx) * 64, c0 = (bid % gx) * 64;
    const int tr = tid >> 4, tc4 = (tid & 15) * 4;
#pragma unroll
    for (int p = 0; p < 4; p++) {
        int r = p * 16 + tr;
        float4 v = *(const float4*)&src[(size_t)(r0 + r) * C + c0 + tc4];
        t[tc4 + 0][r] = f2bf(v.x);
        t[tc4 + 1][r] = f2bf(v.y);
        t[tc4 + 2][r] = f2bf(v.z);
        t[tc4 + 3][r] = f2bf(v.w);
    }
    __syncthreads();
#pragma unroll
    for (int p = 0; p < 4; p++) {
        int cc = p * 16 + tr;
        ushort4 w = *(const ushort4*)&t[cc][tc4];
        *(ushort4*)&dst[(size_t)(c0 + cc) * R + r0 + tc4] = w;
    }
}

// ---------------------------------------------------------------------------
// In-place RoPE on bf16 k only (q is roped inside flash_attn). HW trig.
// ---------------------------------------------------------------------------
__global__ __launch_bounds__(256) void rope_k(u16* __restrict__ k,
                                              const int* __restrict__ kvpos)
{
    int idx = blockIdx.x * 256 + threadIdx.x;
    int rn = idx >> 4;
    int h4 = (idx & 15) * 4;
    int pos = kvpos[rn >> 2];
    u16* base = k + (size_t)rn * HD;
    ushort4 a = *(const ushort4*)&base[h4];
    ushort4 bvec = *(const ushort4*)&base[h4 + 64];
    u16 av[4] = {a.x, a.y, a.z, a.w};
    u16 bv[4] = {bvec.x, bvec.y, bvec.z, bvec.w};
#pragma unroll
    for (int j = 0; j < 4; j++) {
        float rscale = __builtin_amdgcn_exp2f((float)(h4 + j) * -ROPE_L2) * INV_2PI;
        float s, c;
        hw_sincos_rev((float)pos * rscale, &s, &c);
        float x1 = bf2f(av[j]), x2 = bf2f(bv[j]);
        av[j] = f2bf(x1 * c - x2 * s);
        bv[j] = f2bf(x2 * c + x1 * s);
    }
    ushort4 ra, rb;
    ra.x = av[0]; ra.y = av[1]; ra.z = av[2]; ra.w = av[3];
    rb.x = bv[0]; rb.y = bv[1]; rb.z = bv[2]; rb.w = bv[3];
    *(ushort4*)&base[h4] = ra;
    *(ushort4*)&base[h4 + 64] = rb;
}

// ---------------------------------------------------------------------------
// 8-phase 256x256 bf16 GEMM mainloop (4-load slabs, VM8 schedule) — qkv.
// ---------------------------------------------------------------------------
#define GPH(c, ks, mh, STAGE, VMW) do {                                        \
    bf16x8 Af[4];                                                              \
    _Pragma("unroll")                                                          \
    for (int mf = 0; mf < 4; mf++)                                             \
        Af[mf] = *(const bf16x8*)&Ab[c][ks][(arow + (mh) * 64 + mf * 16) * 32 + cxs]; \
    if ((mh) == 0) {                                                           \
        _Pragma("unroll")                                                      \
        for (int nf = 0; nf < 4; nf++)                                         \
            Bf[nf] = *(const bf16x8*)&Bb[c][ks][(brow + nf * 16) * 32 + cxs];  \
    }                                                                          \
    STAGE;                                                                     \
    BARRIER;                                                                   \
    asm volatile("s_waitcnt lgkmcnt(0)" ::: "memory");                         \
    __builtin_amdgcn_s_setprio(1);                                             \
    _Pragma("unroll")                                                          \
    for (int mf = 0; mf < 4; mf++)                                             \
        _Pragma("unroll")                                                      \
        for (int nf = 0; nf < 4; nf++)                                         \
            acc[(mh) * 4 + mf][nf] = __builtin_amdgcn_mfma_f32_16x16x32_bf16(  \
                Af[mf], Bf[nf], acc[(mh) * 4 + mf][nf], 0, 0, 0);              \
    __builtin_amdgcn_s_setprio(0);                                             \
    VMW;                                                                       \
    BARRIER;                                                                   \
} while (0)

__device__ __forceinline__ void gemm8_mainloop(const u16* __restrict__ A,
                                               const u16* __restrict__ Bt,
                                               int m0, int n0,
                                               u16 (&Ab)[2][2][256 * 32],
                                               u16 (&Bb)[2][2][256 * 32],
                                               f32x4 (&acc)[8][4])
{
    const int tid = threadIdx.x;
    const int wv = tid >> 6, lane = tid & 63;
    const int l15 = lane & 15, quad = lane >> 4;
    const int wr = wv >> 2, wc = wv & 3;

#pragma unroll
    for (int mf = 0; mf < 8; mf++)
#pragma unroll
        for (int nf = 0; nf < 4; nf++) acc[mf][nf] = (f32x4){0.f, 0.f, 0.f, 0.f};

    auto stageA = [&](int kt, int kh, int c) {
#pragma unroll
        for (int j = 0; j < 2; j++) {
            int q = j * 512 + tid;
            int r = q >> 2;
            int c4 = (q & 3) ^ (r & 3);
            gload16(A + (size_t)(m0 + r) * 2048 + kt * 64 + kh * 32 + c4 * 8,
                    &Ab[c][kh][q * 8]);
        }
    };
    auto stageB = [&](int kt, int kh, int c) {
#pragma unroll
        for (int j = 0; j < 2; j++) {
            int q = j * 512 + tid;
            int r = q >> 2;
            int c4 = (q & 3) ^ (r & 3);
            gload16(Bt + (size_t)(n0 + r) * 2048 + kt * 64 + kh * 32 + c4 * 8,
                    &Bb[c][kh][q * 8]);
        }
    };

    const int arow = wr * 128 + l15;
    const int brow = wc * 64 + l15;
    const int cxs  = (quad ^ (l15 & 3)) * 8;

    stageA(0, 0, 0); stageB(0, 0, 0);
    stageA(0, 1, 0); stageB(0, 1, 0);
    stageA(1, 0, 1); stageB(1, 0, 1);
    VM8;
    BARRIER;

    bf16x8 Bf[4];
    for (int it = 0; it < 15; it++) {
        const int t0 = 2 * it, t1 = 2 * it + 1;
        GPH(0, 0, 0, { stageA(t1, 1, 1); },     VMNONE);
        GPH(0, 0, 1, { stageB(t1, 1, 1); },     VM8);
        GPH(0, 1, 0, { stageA(t0 + 2, 0, 0); }, VMNONE);
        GPH(0, 1, 1, { stageB(t0 + 2, 0, 0); }, VM8);
        GPH(1, 0, 0, { stageA(t0 + 2, 1, 0); }, VMNONE);
        GPH(1, 0, 1, { stageB(t0 + 2, 1, 0); }, VM8);
        GPH(1, 1, 0, { stageA(t1 + 2, 0, 1); }, VMNONE);
        GPH(1, 1, 1, { stageB(t1 + 2, 0, 1); }, VM8);
    }
    GPH(0, 0, 0, { stageA(31, 1, 1); }, VMNONE);
    GPH(0, 0, 1, { stageB(31, 1, 1); }, VM8);
    GPH(0, 1, 0, VMNONE, VMNONE);
    GPH(0, 1, 1, VMNONE, VM4);
    GPH(1, 0, 0, VMNONE, VMNONE);
    GPH(1, 0, 1, VMNONE, VM0);
    GPH(1, 1, 0, VMNONE, VMNONE);
    GPH(1, 1, 1, VMNONE, VMNONE);
}

// Fused QKV: grid (12, 16) = 192 blocks (XCD-swizzled).
__global__ __launch_bounds__(512, 2) void qkv_gemm8(const u16* __restrict__ Xq,
                                                    const u16* __restrict__ Xkv,
                                                    const u16* __restrict__ Wqt,
                                                    const u16* __restrict__ Wkt,
                                                    const u16* __restrict__ Wvt,
                                                    u16* __restrict__ qraw,
                                                    u16* __restrict__ kraw,
                                                    u16* __restrict__ vt)
{
    __shared__ __align__(16) u16 Ab[2][2][256 * 32];
    __shared__ __align__(16) u16 Bb[2][2][256 * 32];
    f32x4 acc[8][4];

    const int bid0 = (int)blockIdx.x + 12 * (int)blockIdx.y;
    const int swz  = (bid0 & 7) * 24 + (bid0 >> 3);
    const int cx   = swz % 12;
    const int m0   = (swz / 12) * 256;

    const u16 *A, *Bt; int nb;
    if (cx < 8)       { A = Xq;  Bt = Wqt; nb = cx * 256; }
    else if (cx < 10) { A = Xkv; Bt = Wkt; nb = (cx - 8) * 256; }
    else              { A = Xkv; Bt = Wvt; nb = (cx - 10) * 256; }

    gemm8_mainloop(A, Bt, m0, nb, Ab, Bb, acc);

    const int tid = threadIdx.x;
    const int wv = tid >> 6, lane = tid & 63;
    const int l15 = lane & 15, quad = lane >> 4;
    const int wr = wv >> 2, wc = wv & 3;
    const int row0 = m0 + wr * 128;

    if (cx < 10) {
        u16* out; int ldw;
        if (cx < 8) { out = qraw; ldw = 2048; }
        else        { out = kraw; ldw = 512; }
#pragma unroll
        for (int mf = 0; mf < 8; mf++)
#pragma unroll
            for (int nf = 0; nf < 4; nf++) {
                int col = nb + wc * 64 + nf * 16 + l15;
                int r = row0 + mf * 16 + quad * 4;
#pragma unroll
                for (int reg = 0; reg < 4; reg++)
                    out[(size_t)(r + reg) * ldw + col] = f2bf(acc[mf][nf][reg]);
            }
    } else {
        const int b = m0 >> 11;
#pragma unroll
        for (int mf = 0; mf < 8; mf++)
#pragma unroll
            for (int nf = 0; nf < 4; nf++) {
                int col = nb + wc * 64 + nf * 16 + l15;
                int tloc = ((row0 & 2047) + mf * 16 + quad * 4);
                ushort4 w4;
                w4.x = f2bf(acc[mf][nf][0]);
                w4.y = f2bf(acc[mf][nf][1]);
                w4.z = f2bf(acc[mf][nf][2]);
                w4.w = f2bf(acc[mf][nf][3]);
                *(ushort4*)&vt[((size_t)(b * 512 + col)) * 2048 + tloc] = w4;
            }
    }
}

// ---------------------------------------------------------------------------
// 8-phase 256x128 bf16 GEMM mainloop (3-load slabs, VM6 schedule) — oproj.
// Exact isomorphism of gemm8_mainloop: slab = 3 loads (A 2 + B 1), so the
// steady-state queue is 3 slabs x 3 = 9 and counted waits drop 8->6,
// prologue 8->6, tail 8/4/0 -> 6/3/0. Per-wave output 128x32 (acc[8][2]).
// ---------------------------------------------------------------------------
#define GPHN(c, ks, mh, STAGE, VMW) do {                                       \
    bf16x8 Af[4];                                                              \
    _Pragma("unroll")                                                          \
    for (int mf = 0; mf < 4; mf++)                                             \
        Af[mf] = *(const bf16x8*)&Ab[c][ks][(arow + (mh) * 64 + mf * 16) * 32 + cxs]; \
    if ((mh) == 0) {                                                           \
        _Pragma("unroll")                                                      \
        for (int nf = 0; nf < 2; nf++)                                         \
            Bf[nf] = *(const bf16x8*)&Bb[c][ks][(brow + nf * 16) * 32 + cxs];  \
    }                                                                          \
    STAGE;                                                                     \
    BARRIER;                                                                   \
    asm volatile("s_waitcnt lgkmcnt(0)" ::: "memory");                         \
    __builtin_amdgcn_s_setprio(1);                                             \
    _Pragma("unroll")                                                          \
    for (int mf = 0; mf < 4; mf++)                                             \
        _Pragma("unroll")                                                      \
        for (int nf = 0; nf < 2; nf++)                                         \
            acc[(mh) * 4 + mf][nf] = __builtin_amdgcn_mfma_f32_16x16x32_bf16(  \
                Af[mf], Bf[nf], acc[(mh) * 4 + mf][nf], 0, 0, 0);              \
    __builtin_amdgcn_s_setprio(0);                                             \
    VMW;                                                                       \
    BARRIER;                                                                   \
} while (0)

__device__ __forceinline__ void gemm8n_mainloop(const u16* __restrict__ A,
                                                const u16* __restrict__ Bt,
                                                int m0, int n0,
                                                u16 (&Ab)[2][2][256 * 32],
                                                u16 (&Bb)[2][2][128 * 32],
                                                f32x4 (&acc)[8][2])
{
    const int tid = threadIdx.x;
    const int wv = tid >> 6, lane = tid & 63;
    const int l15 = lane & 15, quad = lane >> 4;
    const int wr = wv >> 2, wc = wv & 3;

#pragma unroll
    for (int mf = 0; mf < 8; mf++)
#pragma unroll
        for (int nf = 0; nf < 2; nf++) acc[mf][nf] = (f32x4){0.f, 0.f, 0.f, 0.f};

    auto stageA = [&](int kt, int kh, int c) {
#pragma unroll
        for (int j = 0; j < 2; j++) {
            int q = j * 512 + tid;
            int r = q >> 2;
            int c4 = (q & 3) ^ (r & 3);
            gload16(A + (size_t)(m0 + r) * 2048 + kt * 64 + kh * 32 + c4 * 8,
                    &Ab[c][kh][q * 8]);
        }
    };
    auto stageB = [&](int kt, int kh, int c) {
        int q = tid;                       // 128 rows x 4 chunks = 512
        int r = q >> 2;
        int c4 = (q & 3) ^ (r & 3);
        gload16(Bt + (size_t)(n0 + r) * 2048 + kt * 64 + kh * 32 + c4 * 8,
                &Bb[c][kh][q * 8]);
    };

    const int arow = wr * 128 + l15;
    const int brow = wc * 32 + l15;
    const int cxs  = (quad ^ (l15 & 3)) * 8;

    stageA(0, 0, 0); stageB(0, 0, 0);
    stageA(0, 1, 0); stageB(0, 1, 0);
    stageA(1, 0, 1); stageB(1, 0, 1);
    VM6;
    BARRIER;

    bf16x8 Bf[2];
    for (int it = 0; it < 15; it++) {
        const int t0 = 2 * it, t1 = 2 * it + 1;
        GPHN(0, 0, 0, { stageA(t1, 1, 1); },     VMNONE);
        GPHN(0, 0, 1, { stageB(t1, 1, 1); },     VM6);
        GPHN(0, 1, 0, { stageA(t0 + 2, 0, 0); }, VMNONE);
        GPHN(0, 1, 1, { stageB(t0 + 2, 0, 0); }, VM6);
        GPHN(1, 0, 0, { stageA(t0 + 2, 1, 0); }, VMNONE);
        GPHN(1, 0, 1, { stageB(t0 + 2, 1, 0); }, VM6);
        GPHN(1, 1, 0, { stageA(t1 + 2, 0, 1); }, VMNONE);
        GPHN(1, 1, 1, { stageB(t1 + 2, 0, 1); }, VM6);
    }
    GPHN(0, 0, 0, { stageA(31, 1, 1); }, VMNONE);
    GPHN(0, 0, 1, { stageB(31, 1, 1); }, VM6);
    GPHN(0, 1, 0, VMNONE, VMNONE);
    GPHN(0, 1, 1, VMNONE, VM3);
    GPHN(1, 0, 0, VMNONE, VMNONE);
    GPHN(1, 0, 1, VMNONE, VM0);
    GPHN(1, 1, 0, VMNONE, VMNONE);
    GPHN(1, 1, 1, VMNONE, VMNONE);
}

// Output projection: 256x128 tiles, grid (16,16) = 256 blocks (full machine).
__global__ __launch_bounds__(512, 2) void oproj_gemm8n(const u16* __restrict__ attnb,
                                                       const u16* __restrict__ Wot,
                                                       float* __restrict__ out)
{
    __shared__ __align__(16) u16 Ab[2][2][256 * 32];
    __shared__ __align__(16) u16 Bb[2][2][128 * 32];
    f32x4 acc[8][2];

    const int bid0 = (int)blockIdx.x + 16 * (int)blockIdx.y;
    const int swz  = (bid0 & 7) * 32 + (bid0 >> 3);
    const int n0   = (swz % 16) * 128;
    const int m0   = (swz / 16) * 256;

    gemm8n_mainloop(attnb, Wot, m0, n0, Ab, Bb, acc);

    const int tid = threadIdx.x;
    const int wv = tid >> 6, lane = tid & 63;
    const int l15 = lane & 15, quad = lane >> 4;
    const int wr = wv >> 2, wc = wv & 3;
    const int row0 = m0 + wr * 128;
#pragma unroll
    for (int mf = 0; mf < 8; mf++)
#pragma unroll
        for (int nf = 0; nf < 2; nf++) {
            int col = n0 + wc * 32 + nf * 16 + l15;
            int r = row0 + mf * 16 + quad * 4;
#pragma unroll
            for (int reg = 0; reg < 4; reg++)
                out[(size_t)(r + reg) * 2048 + col] = acc[mf][nf][reg];
        }
}

// ---------------------------------------------------------------------------
// Flash attention v7: v6 with spill-free Q-RoPE — rope the bf16 fragments
// in place with scalar temps + HW trig (no fp32 staging array, no libm).
// ---------------------------------------------------------------------------
__global__ __launch_bounds__(512, 4) void flash_attn_v7(const u16* __restrict__ qh,
                                                        const u16* __restrict__ kh,
                                                        const u16* __restrict__ vtg,
                                                        const int* __restrict__ qpos,
                                                        u16* __restrict__ attnb)
{
    __shared__ __align__(16) u16 Ks[2][64 * 128];
    __shared__ __align__(16) u16 Vt[2][128 * 64];
    __shared__ __align__(16) u16 Ps[128 * 64];

    const int yy = blockIdx.y;
    const int qt = (yy < 8) ? (15 - yy) : (yy - 8);   // balanced pairing
    const int bh = blockIdx.x;
    const int b = bh >> 4, n = bh & 15, kvh = n >> 2;
    const int q0 = qt * 128;
    const int tid = threadIdx.x;
    const int wv = tid >> 6, lane = tid & 63;          // wv in 0..7
    const int l15 = lane & 15, quad = lane >> 4;

    const size_t kbase = (size_t)(b * Tdim) * 512 + kvh * 128;
    const size_t vbase = ((size_t)(b * 512 + kvh * 128)) * 2048;
    const int nT = 2 * qt + 2;

    auto stage = [&](int t, int buf) {
        const int s0s = t * 64;
#pragma unroll
        for (int c = 0; c < 2; c++) {
            int j = c * 512 + tid;        // 0..1023
            int s = j >> 4;               // 0..63
            int c8 = (j & 15) ^ (s & 7);
            gload16(kh + kbase + (size_t)(s0s + s) * 512 + c8 * 8,
                    &Ks[buf][(c * 512 + wv * 64) * 8]);
            int h = j >> 3;               // 0..127
            int sb = (j & 7) ^ (h & 7);
            gload16(vtg + vbase + (size_t)h * 2048 + s0s + sb * 8,
                    &Vt[buf][(c * 512 + wv * 64) * 8]);
        }
    };

    stage(0, 0);

    // ---- Q fragments + fused RoPE, in place (overlaps tile-0 staging) ----
    bf16x8 qfrag[4];
    {
        const size_t qbase = ((size_t)(b * Tdim + q0 + wv * 16)) * 2048 + n * 128;
#pragma unroll
        for (int kt = 0; kt < 4; kt++)
            qfrag[kt] = *(const bf16x8*)(qh + qbase + (size_t)l15 * 2048
                                          + kt * 32 + quad * 8);
        const float fpos = (float)qpos[b * Tdim + q0 + wv * 16 + l15];
#pragma unroll
        for (int kt = 0; kt < 2; kt++)
#pragma unroll
            for (int j = 0; j < 8; j++) {
                int h = kt * 32 + quad * 8 + j;     // in [0,64)
                float rscale = __builtin_amdgcn_exp2f((float)h * -ROPE_L2) * INV_2PI;
                float s, c;
                hw_sincos_rev(fpos * rscale, &s, &c);
                s *= QPRESCALE; c *= QPRESCALE;
                float x1 = (float)qfrag[kt][j], x2 = (float)qfrag[kt + 2][j];
                qfrag[kt][j]     = (__bf16)(x1 * c - x2 * s);
                qfrag[kt + 2][j] = (__bf16)(x2 * c + x1 * s);
            }
    }

    f32x4 Oacc[8];
#pragma unroll
    for (int ht = 0; ht < 8; ht++) Oacc[ht] = (f32x4){0.f, 0.f, 0.f, 0.f};
    float mrow = NEG_INF;
    float lrow = 0.f;

    __syncthreads();   // tile 0 staged

    int cur = 0;
    for (int t = 0; t < nT; t++) {
        const int s0 = t * 64;

        if (t + 1 < nT) stage(t + 1, cur ^ 1);

        f32x4 S[4];
#pragma unroll
        for (int nt = 0; nt < 4; nt++) S[nt] = (f32x4){0.f, 0.f, 0.f, 0.f};
#pragma unroll
        for (int kt = 0; kt < 4; kt++) {
            bf16x8 kf[4];
#pragma unroll
            for (int nt = 0; nt < 4; nt++) {
                int s = nt * 16 + l15;
                int cb = (kt * 4 + quad) ^ (s & 7);
                kf[nt] = *(const bf16x8*)&Ks[cur][s * 128 + cb * 8];
            }
#pragma unroll
            for (int nt = 0; nt < 4; nt++)
                S[nt] = __builtin_amdgcn_mfma_f32_16x16x32_bf16(kf[nt], qfrag[kt], S[nt], 0, 0, 0);
        }

        const bool domask = (t >= nT - 2);
        const int m_l = wv * 16 + l15;
        const int mg = q0 + m_l;
        float sv[16];
#pragma unroll
        for (int nt = 0; nt < 4; nt++)
#pragma unroll
            for (int r = 0; r < 4; r++) {
                float vv = S[nt][r];
                if (domask) {
                    int sg = s0 + nt * 16 + quad * 4 + r;
                    if (sg > mg) vv = NEG_INF;
                }
                sv[nt * 4 + r] = vv;
            }
        float mx = quad_reduce_max(tree_max16(sv));
        const bool skip = __all(mx <= mrow + DEFER_THR);
        const float mNew = skip ? mrow : fmaxf(mrow, mx);
#pragma unroll
        for (int i = 0; i < 16; i++)
            sv[i] = __builtin_amdgcn_exp2f(sv[i] - mNew);
#pragma unroll
        for (int nt = 0; nt < 4; nt++) {
            int sb = nt * 2 + (quad >> 1);
            int cb = sb ^ (m_l & 7);
            ushort4 pw;
            pw.x = f2bfn(sv[nt * 4 + 0]);
            pw.y = f2bfn(sv[nt * 4 + 1]);
            pw.z = f2bfn(sv[nt * 4 + 2]);
            pw.w = f2bfn(sv[nt * 4 + 3]);
            *(ushort4*)&Ps[m_l * 64 + cb * 8 + (quad & 1) * 4] = pw;
        }
        {
            float ps = quad_reduce_sum(tree_sum16(sv));
            if (skip) {
                lrow += ps;
            } else {
                float alpha = __builtin_amdgcn_exp2f(mrow - mNew);
                mrow = mNew;
                lrow = lrow * alpha + ps;
                float a0 = __shfl(alpha, quad * 4 + 0);
                float a1 = __shfl(alpha, quad * 4 + 1);
                float a2 = __shfl(alpha, quad * 4 + 2);
                float a3 = __shfl(alpha, quad * 4 + 3);
#pragma unroll
                for (int ht = 0; ht < 8; ht++) {
                    Oacc[ht][0] *= a0;
                    Oacc[ht][1] *= a1;
                    Oacc[ht][2] *= a2;
                    Oacc[ht][3] *= a3;
                }
            }
        }

#pragma unroll
        for (int k2 = 0; k2 < 2; k2++) {
            int cbp = (k2 * 4 + quad) ^ (m_l & 7);
            bf16x8 pf = *(const bf16x8*)&Ps[m_l * 64 + cbp * 8];
#pragma unroll
            for (int ht = 0; ht < 8; ht++) {
                int h = ht * 16 + l15;
                int cb = (k2 * 4 + quad) ^ (h & 7);
                bf16x8 vf = *(const bf16x8*)&Vt[cur][h * 64 + cb * 8];
                Oacc[ht] = __builtin_amdgcn_mfma_f32_16x16x32_bf16(pf, vf, Oacc[ht], 0, 0, 0);
            }
        }

        __syncthreads();
        cur ^= 1;
    }

    {
        f32x4 inv;
#pragma unroll
        for (int r = 0; r < 4; r++)
            inv[r] = 1.0f / __shfl(lrow, quad * 4 + r);
        int mg0 = q0 + wv * 16 + quad * 4;
        u16* dst0 = attnb + ((size_t)(b * Tdim + mg0)) * 2048 + n * 128 + l15;
#pragma unroll
        for (int ht = 0; ht < 8; ht++) {
#pragma unroll
            for (int r = 0; r < 4; r++)
                dst0[(size_t)r * 2048 + ht * 16] = f2bfn(Oacc[ht][r] * inv[r]);
        }
    }
}

extern "C" void kernel_launch(void* const* d_in, const int* in_sizes, int n_in,
                              void* d_out, int out_size, void* d_ws, size_t ws_size,
                              hipStream_t stream) {
    const float* Xq    = (const float*)d_in[0];
    const float* Xkv   = (const float*)d_in[1];
    const int*   qpos  = (const int*)d_in[2];
    const int*   kvpos = (const int*)d_in[3];
    const float* Wq    = (const float*)d_in[4];
    const float* Wk    = (const float*)d_in[5];
    const float* Wv    = (const float*)d_in[6];
    const float* Wo    = (const float*)d_in[7];
    float* out = (float*)d_out;

    char* w = (char*)d_ws;
    u16* xq_bf = (u16*)(w);                    // 16 MB
    u16* xkv_bf= (u16*)(w + (16u << 20));      // 16 MB
    u16* qraw  = (u16*)(w + (32u << 20));      // 16 MB (un-roped; flash ropes)
    u16* kraw  = (u16*)(w + (48u << 20));      //  4 MB (roped in place by rope_k)
    u16* vt    = (u16*)(w + (52u << 20));      //  4 MB [(b*4+kvh)*128+h][2048]
    u16* wq_t  = (u16*)(w + (56u << 20));      //  8 MB
    u16* wk_t  = (u16*)(w + (64u << 20));      //  2 MB
    u16* wv_t  = (u16*)(w + (66u << 20));      //  2 MB
    u16* wo_t  = (u16*)(w + (68u << 20));      //  8 MB
    u16* attnb = (u16*)(w);                    // aliases xq_bf (dead by then)

    prep_all<<<10752, 256, 0, stream>>>(Xq, Xkv, Wq, Wk, Wv, Wo,
                                        xq_bf, xkv_bf, wq_t, wk_t, wv_t, wo_t);
    qkv_gemm8<<<dim3(12, 16), 512, 0, stream>>>(xq_bf, xkv_bf, wq_t, wk_t, wv_t,
                                                qraw, kraw, vt);
    rope_k<<<1024, 256, 0, stream>>>(kraw, kvpos);
    flash_attn_v7<<<dim3(32, 16), 512, 0, stream>>>(qraw, kraw, vt, qpos, attnb);
    oproj_gemm8n<<<dim3(16, 16), 512, 0, stream>>>(attnb, wo_t, out);
}